// Round 9
// baseline (5513.916 us; speedup 1.0000x reference)
//
#include <hip/hip_runtime.h>
#include <hip/hip_bf16.h>
#include <hip/hip_fp8.h>

// Problem constants (fixed by the bench: B=32, T0=50, F=171, H=1024, G=300)
#define Bn   32
#define Fdim 171
#define XPAD 256             // x-region padded to 16 tiles of 16 (conditioned phase)
#define Hdim 1024
#define NG   4096            // 4*H gate rows
#define K1p  1280            // layer1 conditioned K = XPAD+H (80 tiles)
#define K1g  2048            // layer1 generative K = H(h2 via Wcomb) + H(h0)
#define K2c  2048            // layer2/3 K = 2H (128 tiles)
#define KDd  1024            // decoder K = H
#define WDR  176             // decoder rows padded 171 -> 176
#define NBLK 192             // persistent grid: 3 layers x 64 unit-tiles
#define S1e  (80 * 512)      // ab1 slot BYTES (fp8, tiled [80][32][16])
#define S2e  (128 * 512)     // ab2/ab3 slot BYTES (tiled [128][32][16])

// fp8 scaling: weights *64, activations *16, both exact powers of 2.
#define SW    64.0f
#define SA    16.0f
#define INVS  (1.0f / (SW * SA))

typedef __attribute__((ext_vector_type(4))) float f32x4;
typedef unsigned char fp8;

// ---------------- static workspace layout (bytes); ab buffers are tail ----
#define ALIGN256(x) ((((size_t)(x)) + 255) & ~(size_t)255)
constexpr size_t OFF_W1  = 0;
constexpr size_t OFF_W1G = ALIGN256(OFF_W1 + (size_t)NG * K1p);
constexpr size_t OFF_W2  = ALIGN256(OFF_W1G + (size_t)NG * K1g);
constexpr size_t OFF_W3  = ALIGN256(OFF_W2 + (size_t)NG * K2c);
constexpr size_t OFF_WD  = ALIGN256(OFF_W3 + (size_t)NG * K2c);
constexpr size_t OFF_B1  = ALIGN256(OFF_WD + (size_t)WDR * KDd);
constexpr size_t OFF_B1G = ALIGN256(OFF_B1 + (size_t)NG * 4);
constexpr size_t OFF_B2  = ALIGN256(OFF_B1G + (size_t)NG * 4);
constexpr size_t OFF_B3  = ALIGN256(OFF_B2 + (size_t)NG * 4);
constexpr size_t OFF_BD  = ALIGN256(OFF_B3 + (size_t)NG * 4);
constexpr size_t OFF_CB  = ALIGN256(OFF_BD + (size_t)WDR * 4);
constexpr size_t OFF_BAR = ALIGN256(OFF_CB + (size_t)3 * Bn * Hdim * 4);
constexpr size_t OFF_AB1 = ALIGN256(OFF_BAR + 16384);   // bar region: 4096 u32
// ab1: D*S1e; ab2: D*S2e; ab3: D*S2e  (D chosen from ws_size; <=32)

// progress flags: one u32 per 64B line, one per block.
// flag[b] = t+1  <=>  block b finished step t (its slot (t+1)&dm writes are acked).
#define FLG(i)  ((i) * 16)

// gate-interleaved packed row: pr = u*64 + q*16 + rr  <->  orig row = q*1024 + u*16 + rr
__device__ __forceinline__ int orig_row(int pr) {
    int u = pr >> 6, q = (pr >> 4) & 3, rr = pr & 15;
    return q * Hdim + u * 16 + rr;
}

__device__ __forceinline__ float sigm(float x) { return 1.f / (1.f + __expf(-x)); }
// overflow-safe fast tanh: e^{-2|x|} never overflows; large |c| -> +-1 exactly.
__device__ __forceinline__ float ftanh(float x) {
    float e = __expf(-2.f * fabsf(x));
    float t = (1.f - e) / (1.f + e);
    return x >= 0.f ? t : -t;
}

__device__ __forceinline__ unsigned char f2fp8(float x) {  // OCP e4m3, RNE+sat
    __hip_fp8_e4m3 q(x);
    return (unsigned char)q.__x;
}

__device__ __forceinline__ long ld8b(const fp8* p) {   // plain cached 8B load
    return *reinterpret_cast<const long*>(p);
}
// Coherent write-through stores (agent scope, relaxed): reach the coherence
// point, no cache-wide maintenance; readers use plain cached loads + rotation.
__device__ __forceinline__ void st1c(fp8* p, unsigned char v) {
    __hip_atomic_store((unsigned char*)p, v, __ATOMIC_RELAXED, __HIP_MEMORY_SCOPE_AGENT);
}
__device__ __forceinline__ void stu64(unsigned long long* p, unsigned long long v) {
    __hip_atomic_store(p, v, __ATOMIC_RELAXED, __HIP_MEMORY_SCOPE_AGENT);
}
__device__ __forceinline__ unsigned ldflag(const unsigned* p) {
    return __hip_atomic_load(p, __ATOMIC_RELAXED, __HIP_MEMORY_SCOPE_AGENT);
}
__device__ __forceinline__ void stflag(unsigned* p, unsigned v) {
    __hip_atomic_store(p, v, __ATOMIC_RELAXED, __HIP_MEMORY_SCOPE_AGENT);
}
__device__ __forceinline__ f32x4 mfma8(long a, long b, f32x4 c) {
    return __builtin_amdgcn_mfma_f32_16x16x32_fp8_fp8(a, b, c, 0, 0, 0);
}

// per-wave dataflow wait: lanes with idx>=0 require flag[idx] >= tgt(lane).
__device__ __forceinline__ void pollgen(unsigned* bar, int idx, unsigned tgt) {
    for (;;) {
        bool ok = true;
        if (idx >= 0) ok = (ldflag(&bar[FLG(idx)]) >= tgt);
        if (__all(ok)) break;
        __builtin_amdgcn_s_sleep(1);
    }
    asm volatile("" ::: "memory");
}

// A-fragment loads from tiled [k/16][b][16] fp8 state
template <int NF>
__device__ __forceinline__ void aload(const fp8* __restrict__ As, int k0,
                                      int col, int kb8, long (&a0)[NF], long (&a1)[NF]) {
#pragma unroll
    for (int i = 0; i < NF; ++i) {
        int k = k0 + i * 32 + kb8;
        const fp8* ap = As + (size_t)(k >> 4) * 512 + (k & 15);
        a0[i] = ld8b(ap + col * 16);
        a1[i] = ld8b(ap + (col + 16) * 16);
    }
}
// weight stream + MFMA accumulate (weights row-linear [gate_row][K])
template <int K, int NF>
__device__ __forceinline__ void wstream(const fp8* __restrict__ Wrow, int k0,
                                        int col, int kb8,
                                        const long (&a0)[NF], const long (&a1)[NF],
                                        f32x4 (&acc)[2][4]) {
#pragma unroll
    for (int i = 0; i < NF; ++i) {
        const fp8* wp = Wrow + (size_t)col * K + k0 + i * 32 + kb8;
#pragma unroll
        for (int q = 0; q < 4; ++q) {
            long bq = ld8b(wp + (size_t)q * 16 * K);
            acc[0][q] = mfma8(a0[i], bq, acc[0][q]);
            acc[1][q] = mfma8(a1[i], bq, acc[1][q]);
        }
    }
}

// ---------------- prep kernels ----------------
__global__ void k_pack_w1(const float* Wih, const float* Whh, fp8* dst) {
    const size_t n = (size_t)NG * K1p;
    for (size_t i = (size_t)blockIdx.x * blockDim.x + threadIdx.x; i < n;
         i += (size_t)gridDim.x * blockDim.x) {
        int pr = (int)(i / K1p), k = (int)(i % K1p);
        int ro = orig_row(pr);
        float v = 0.f;
        if (k < Fdim)       v = Wih[(size_t)ro * Fdim + k];
        else if (k >= XPAD) v = Whh[(size_t)ro * Hdim + (k - XPAD)];
        dst[i] = f2fp8(v * SW);
    }
}

__global__ void k_pack_w23(const float* Wih, const float* Whh, fp8* dst) {
    const size_t n = (size_t)NG * K2c;
    for (size_t i = (size_t)blockIdx.x * blockDim.x + threadIdx.x; i < n;
         i += (size_t)gridDim.x * blockDim.x) {
        int pr = (int)(i / K2c), k = (int)(i % K2c);
        int ro = orig_row(pr);
        float v = (k < Hdim) ? Wih[(size_t)ro * Hdim + k]
                             : Whh[(size_t)ro * Hdim + (k - Hdim)];
        dst[i] = f2fp8(v * SW);
    }
}

// generative layer-1 weights: cols 0..1023 = Wcomb = W1x @ Wd  (decoder folded
// into the recurrence), cols 1024..2047 = Whh1.
__global__ void k_pack_w1g(const float* Wih, const float* Whh, const float* Wd,
                           fp8* dst) {
    const size_t n = (size_t)NG * K1g;
    for (size_t i = (size_t)blockIdx.x * blockDim.x + threadIdx.x; i < n;
         i += (size_t)gridDim.x * blockDim.x) {
        int pr = (int)(i >> 11), k = (int)(i & 2047);
        int ro = orig_row(pr);
        float v;
        if (k < 1024) {
            float acc = 0.f;
            for (int f = 0; f < Fdim; ++f)
                acc += Wih[(size_t)ro * Fdim + f] * Wd[(size_t)f * KDd + k];
            v = acc;
        } else {
            v = Whh[(size_t)ro * Hdim + (k - 1024)];
        }
        dst[i] = f2fp8(v * SW);
    }
}

__global__ void k_pack_wd(const float* Wd, fp8* dst) {
    const size_t n = (size_t)WDR * KDd;
    for (size_t i = (size_t)blockIdx.x * blockDim.x + threadIdx.x; i < n;
         i += (size_t)gridDim.x * blockDim.x) {
        int r = (int)(i / KDd), k = (int)(i % KDd);
        float v = (r < Fdim) ? Wd[(size_t)r * KDd + k] : 0.f;
        dst[i] = f2fp8(v * SW);
    }
}

__global__ void k_pack_bias(const float* bi1, const float* bh1,
                            const float* bi2, const float* bh2,
                            const float* bi3, const float* bh3,
                            const float* bd,
                            float* B1, float* B2, float* B3, float* BD) {
    const int n = 3 * NG + WDR;
    for (int i = blockIdx.x * blockDim.x + threadIdx.x; i < n;
         i += gridDim.x * blockDim.x) {
        if (i < NG)            { int ro = orig_row(i);        B1[i]        = bi1[ro] + bh1[ro]; }
        else if (i < 2 * NG)   { int ro = orig_row(i - NG);   B2[i - NG]   = bi2[ro] + bh2[ro]; }
        else if (i < 3 * NG)   { int ro = orig_row(i - 2*NG); B3[i - 2*NG] = bi3[ro] + bh3[ro]; }
        else { int r = i - 3 * NG; BD[r] = (r < Fdim) ? bd[r] : 0.f; }
    }
}

// b1g = b1 + W1x @ bd  (exact f32)
__global__ void k_pack_b1g(const float* bi1, const float* bh1,
                           const float* Wih, const float* bd, float* B1G) {
    for (int pr = blockIdx.x * blockDim.x + threadIdx.x; pr < NG;
         pr += gridDim.x * blockDim.x) {
        int ro = orig_row(pr);
        float acc = bi1[ro] + bh1[ro];
        for (int f = 0; f < Fdim; ++f)
            acc += Wih[(size_t)ro * Fdim + f] * bd[f];
        B1G[pr] = acc;
    }
}

// zero all rotating state slots with coherent stores (no cached copies anywhere)
__global__ void k_init(fp8* ab1, fp8* ab2, fp8* ab3, float* cb, unsigned* bar, int D) {
    const size_t n1 = (size_t)D * (S1e / 8);   // u64 count
    const size_t n2 = (size_t)D * (S2e / 8);
    const size_t nc = 3 * Bn * Hdim;
    const size_t tot = n1 + 2 * n2 + nc + 4096;
    for (size_t i = (size_t)blockIdx.x * blockDim.x + threadIdx.x; i < tot;
         i += (size_t)gridDim.x * blockDim.x) {
        if (i < n1)             stu64((unsigned long long*)ab1 + i, 0ull);
        else if (i < n1 + n2)   stu64((unsigned long long*)ab2 + (i - n1), 0ull);
        else if (i < n1 + 2*n2) stu64((unsigned long long*)ab3 + (i - n1 - n2), 0ull);
        else if (i < n1 + 2*n2 + nc) cb[i - n1 - 2*n2] = 0.f;
        else bar[i - n1 - 2*n2 - nc] = 0u;
    }
}

// stage x(0) into slot 0 (tiled layout), coherent, scaled by SA
__global__ void k_stage0(const float* xseq, fp8* ab1, int T0) {
    for (int idx = blockIdx.x * blockDim.x + threadIdx.x; idx < Bn * 11 * 16;
         idx += gridDim.x * blockDim.x) {
        int fu = idx >> 9, rem = idx & 511, b = rem >> 4, jj = rem & 15;
        int f = fu * 16 + jj;
        if (f < Fdim)
            st1c(&ab1[idx], f2fp8(xseq[(size_t)b * T0 * Fdim + f] * SA));
    }
}

__global__ void k_copy_orig(const float* xseq, float* out, int T, int T0) {
    const int n = Bn * T0 * Fdim;
    const size_t base = (size_t)Bn * T * Fdim;
    for (int i = blockIdx.x * blockDim.x + threadIdx.x; i < n;
         i += gridDim.x * blockDim.x) {
        out[base + i] = xseq[i];
    }
}

// ---------------- persistent LSTM kernel (dataflow-synced) ----------------
// grid = 192 x 512 threads (8 waves). block -> (layer = bid/64, ut = bid%64).
// NO global barrier: each wave polls only the <=16 producer blocks of its own
// K-chunk (progress flags, padded lines). Producer flag lands while consumers
// are still in their own elementwise/publish -> sync latency overlaps.
// Skew bound: L1 waits L0, L2 waits L1, L0-gen waits L2 (cycle => spread<=2);
// L0-cond additionally waits mirror L2 flag >= t-2. D>=4 suffices.
// Decoder (blocks 64..74) deferred one step into poll slack; post-loop pass.
__global__ __launch_bounds__(512, 1) void k_lstm(
    const float* __restrict__ xseq, float* __restrict__ out,
    const fp8* __restrict__ W1, const fp8* __restrict__ W1G,
    const fp8* __restrict__ W2, const fp8* __restrict__ W3,
    const fp8* __restrict__ WD,
    const float* __restrict__ b1, const float* __restrict__ b1g,
    const float* __restrict__ b2, const float* __restrict__ b3,
    const float* __restrict__ bdp,
    fp8* ab1, fp8* ab2, fp8* ab3, float* cb,
    unsigned* bar, int T0, int T, int dm) {
    __shared__ float red[8][32][66];

    const int tid = threadIdx.x;
    const int w = tid >> 6;
    const int lane = tid & 63;
    const int col = lane & 15;
    const int kb8 = (lane >> 4) << 3;
    const int bid = blockIdx.x;
    const int layer = bid >> 6;
    const int ut = bid & 63;
    const bool isdec = (bid >= 64 && bid < 75);  // decoder n-tile owners
    const int dnt = bid - 64;

    const float* bl0 = (layer == 0) ? b1 : (layer == 1) ? b2 : b3;
    const fp8* Wl = (layer == 1) ? W2 : W3;

    // elementwise mapping: eb = w + 8*(lane>>4) makes BOTH the acc dump
    // (rows +4 apart -> bank offsets 0/8/16/24) and the reduce read
    // (eb +8 apart -> bank offsets 0/16) 2-lanes-per-bank = conflict-free.
    const int eb = w + 8 * (lane >> 4);
    const int ejj = lane & 15;

    for (int t = 0; t < T; ++t) {
        const int st = t & dm;
        const int ns = (t + 1) & dm;

        // ---------- per-wave producer wait + A load + gate GEMM ----------
        f32x4 acc[2][4] = {};
        if (layer == 0) {
            if (t < T0) {
                // h producers: L0 blocks 8w..8w+7; x producer: bid 11 staging.
                // mirror (lane 9): L2 block ut >= t-2 bounds forward skew.
                int pidx = -1; unsigned ptgt = (unsigned)t;
                if (lane < 8)        pidx = 8 * w + lane;
                else if (lane == 8)  pidx = 11;
                else if (lane == 9 && t >= 2) { pidx = 128 + ut; ptgt = (unsigned)(t - 2); }
                pollgen(bar, pidx, ptgt);
                const fp8* As = ab1 + (size_t)st * S1e;
                const fp8* Wrow = W1 + (size_t)(ut * 64) * K1p;
                long h0v[4], h1v[4];
                aload<4>(As, XPAD + w * 128, col, kb8, h0v, h1v);
                wstream<K1p, 4>(Wrow, XPAD + w * 128, col, kb8, h0v, h1v, acc);
                long x0[1], x1[1];
                aload<1>(As, w * 32, col, kb8, x0, x1);
                wstream<K1p, 1>(Wrow, w * 32, col, kb8, x0, x1, acc);
            } else {
                // generative: A = [h2 | h0]; producers L2 (w<4) / L0 (w>=4).
                int pidx = (lane < 16)
                    ? ((w < 4) ? 128 + 16 * w + lane : 16 * (w - 4) + lane) : -1;
                pollgen(bar, pidx, (unsigned)t);
                long a0[8], a1[8];
                if (w < 4)
                    aload<8>(ab3 + (size_t)st * S2e + 64 * 512, w * 256, col, kb8, a0, a1);
                else
                    aload<8>(ab1 + (size_t)st * S1e + 16 * 512, (w - 4) * 256, col, kb8, a0, a1);
                const fp8* Wrow = W1G + (size_t)(ut * 64) * K1g;
                wstream<K1g, 8>(Wrow, w * 256, col, kb8, a0, a1, acc);
            }
        } else if (layer == 1) {
            // A = ab2 = [h0 | h1]; producers L0 (w<4) / L1 (w>=4).
            int pidx = (lane < 16)
                ? ((w < 4) ? 16 * w + lane : 64 + 16 * (w - 4) + lane) : -1;
            pollgen(bar, pidx, (unsigned)t);
            long a0[8], a1[8];
            aload<8>(ab2 + (size_t)st * S2e, w * 256, col, kb8, a0, a1);
            const fp8* Wrow = W2 + (size_t)(ut * 64) * K2c;
            wstream<K2c, 8>(Wrow, w * 256, col, kb8, a0, a1, acc);
        } else {
            // A = ab3 = [h1 | h2]; producers L1 (w<4) / L2 (w>=4).
            int pidx = (lane < 16)
                ? ((w < 4) ? 64 + 16 * w + lane : 128 + 16 * (w - 4) + lane) : -1;
            pollgen(bar, pidx, (unsigned)t);
            long a0[8], a1[8];
            aload<8>(ab3 + (size_t)st * S2e, w * 256, col, kb8, a0, a1);
            const fp8* Wrow = W3 + (size_t)(ut * 64) * K2c;
            wstream<K2c, 8>(Wrow, w * 256, col, kb8, a0, a1, acc);
        }

        __syncthreads();  // red[] free (previous readers done)
#pragma unroll
        for (int mt = 0; mt < 2; ++mt)
#pragma unroll
            for (int q = 0; q < 4; ++q)
#pragma unroll
                for (int r = 0; r < 4; ++r)
                    red[w][mt * 16 + (lane >> 4) * 4 + r][q * 16 + col] = acc[mt][q][r];
        __syncthreads();

        {   // gates + elementwise c/h update (one (eb,ejj) per thread)
            const float* bl = (layer == 0 && t >= T0) ? b1g : bl0;
            float s[4];
#pragma unroll
            for (int q = 0; q < 4; ++q) {
                float a = 0.f;
#pragma unroll
                for (int ww = 0; ww < 8; ++ww) a += red[ww][eb][q * 16 + ejj];
                s[q] = a * INVS + bl[ut * 64 + q * 16 + ejj];
            }
            size_t cidx = ((size_t)layer * Bn + eb) * Hdim + ut * 16 + ejj;
            float cold = cb[cidx];
            float cn = sigm(s[1]) * cold + sigm(s[0]) * ftanh(s[2]);
            float hn = sigm(s[3]) * ftanh(cn);
            cb[cidx] = cn;
            unsigned char hq = f2fp8(hn * SA);
            const int off = eb * 16 + ejj;
            if (layer == 0) {
                st1c(ab1 + (size_t)ns * S1e + (16 + ut) * 512 + off, hq);
                st1c(ab2 + (size_t)ns * S2e + ut * 512 + off, hq);
            } else if (layer == 1) {
                st1c(ab2 + (size_t)ns * S2e + (64 + ut) * 512 + off, hq);
                st1c(ab3 + (size_t)ns * S2e + ut * 512 + off, hq);
            } else {
                st1c(ab3 + (size_t)ns * S2e + (64 + ut) * 512 + off, hq);
            }
        }

        if (bid == 11 && t + 1 < T0) {  // stage conditioned x(t+1), tiled
            fp8* dst = ab1 + (size_t)ns * S1e;
            for (int idx = tid; idx < Bn * 11 * 16; idx += 512) {
                int fu = idx >> 9, rem = idx & 511, b = rem >> 4, jj = rem & 15;
                int f = fu * 16 + jj;
                if (f < Fdim)
                    st1c(dst + idx,
                         f2fp8(xseq[((size_t)b * T0 + t + 1) * Fdim + f] * SA));
            }
        }

        __syncthreads();  // drain ALL waves' publish stores (vmcnt at barrier)
        if (tid == 0) stflag(&bar[FLG(bid)], (unsigned)(t + 1));

        // ---------- deferred decoder: out(t-1) from h2(t-1) in slot st ----------
        if (isdec && t >= 1) {
            // producers: L2 blocks 8w..8w+7 must have finished step t-1.
            int pidx = (lane < 8) ? 128 + 8 * w + lane : -1;
            pollgen(bar, pidx, (unsigned)t);
            const fp8* Ad = ab3 + (size_t)st * S2e + 64 * 512;
            const fp8* Wrowd = WD + (size_t)(dnt * 16) * KDd;
            long d0[4], d1[4];
            aload<4>(Ad, w * 128, col, kb8, d0, d1);
            f32x4 dacc[2] = {};
#pragma unroll
            for (int i = 0; i < 4; ++i) {
                long bq = ld8b(Wrowd + (size_t)col * KDd + w * 128 + i * 32 + kb8);
                dacc[0] = mfma8(d0[i], bq, dacc[0]);
                dacc[1] = mfma8(d1[i], bq, dacc[1]);
            }
            __syncthreads();
#pragma unroll
            for (int mt = 0; mt < 2; ++mt)
#pragma unroll
                for (int r = 0; r < 4; ++r)
                    red[w][mt * 16 + (lane >> 4) * 4 + r][col] = dacc[mt][r];
            __syncthreads();
            {
                int f = dnt * 16 + ejj;
                float v = 0.f;
#pragma unroll
                for (int ww = 0; ww < 8; ++ww) v += red[ww][eb][ejj];
                v = v * INVS + bdp[f];
                if (f < Fdim)
                    out[(size_t)eb * ((size_t)T * Fdim) + (size_t)(t - 1) * Fdim + f] = v;
            }
        }
    }

    // ---------- post-loop decoder pass: out(T-1) from h2(T-1) in slot T&dm ----
    if (isdec) {
        int pidx = (lane < 8) ? 128 + 8 * w + lane : -1;
        pollgen(bar, pidx, (unsigned)T);
        const int sl = T & dm;
        const fp8* Ad = ab3 + (size_t)sl * S2e + 64 * 512;
        const fp8* Wrowd = WD + (size_t)(dnt * 16) * KDd;
        long d0[4], d1[4];
        aload<4>(Ad, w * 128, col, kb8, d0, d1);
        f32x4 dacc[2] = {};
#pragma unroll
        for (int i = 0; i < 4; ++i) {
            long bq = ld8b(Wrowd + (size_t)col * KDd + w * 128 + i * 32 + kb8);
            dacc[0] = mfma8(d0[i], bq, dacc[0]);
            dacc[1] = mfma8(d1[i], bq, dacc[1]);
        }
        __syncthreads();
#pragma unroll
        for (int mt = 0; mt < 2; ++mt)
#pragma unroll
            for (int r = 0; r < 4; ++r)
                red[w][mt * 16 + (lane >> 4) * 4 + r][col] = dacc[mt][r];
        __syncthreads();
        {
            int f = dnt * 16 + ejj;
            float v = 0.f;
#pragma unroll
            for (int ww = 0; ww < 8; ++ww) v += red[ww][eb][ejj];
            v = v * INVS + bdp[f];
            if (f < Fdim)
                out[(size_t)eb * ((size_t)T * Fdim) + (size_t)(T - 1) * Fdim + f] = v;
        }
    }
}

// ---------------- host launch ----------------
extern "C" void kernel_launch(void* const* d_in, const int* in_sizes, int n_in,
                              void* d_out, int out_size, void* d_ws, size_t ws_size,
                              hipStream_t stream) {
    const float* xseq = (const float*)d_in[0];
    const float* Wih1 = (const float*)d_in[2];
    const float* Whh1 = (const float*)d_in[3];
    const float* bih1 = (const float*)d_in[4];
    const float* bhh1 = (const float*)d_in[5];
    const float* Wih2 = (const float*)d_in[6];
    const float* Whh2 = (const float*)d_in[7];
    const float* bih2 = (const float*)d_in[8];
    const float* bhh2 = (const float*)d_in[9];
    const float* Wih3 = (const float*)d_in[10];
    const float* Whh3 = (const float*)d_in[11];
    const float* bih3 = (const float*)d_in[12];
    const float* bhh3 = (const float*)d_in[13];
    const float* Wd   = (const float*)d_in[14];
    const float* bd   = (const float*)d_in[15];

    const int T0 = in_sizes[0] / (Bn * Fdim);                 // 50
    const int T  = out_size / (Bn * Fdim) - T0;               // 350

    char* ws = (char*)d_ws;
    fp8*   pW1  = (fp8*)(ws + OFF_W1);
    fp8*   pW1G = (fp8*)(ws + OFF_W1G);
    fp8*   pW2  = (fp8*)(ws + OFF_W2);
    fp8*   pW3  = (fp8*)(ws + OFF_W3);
    fp8*   pWD  = (fp8*)(ws + OFF_WD);
    float* pB1  = (float*)(ws + OFF_B1);
    float* pB1G = (float*)(ws + OFF_B1G);
    float* pB2  = (float*)(ws + OFF_B2);
    float* pB3  = (float*)(ws + OFF_B3);
    float* pBD  = (float*)(ws + OFF_BD);
    float* cbp  = (float*)(ws + OFF_CB);
    unsigned* bar = (unsigned*)(ws + OFF_BAR);
    float* out = (float*)d_out;

    // rotation depth: largest power-of-2 D (<=32) whose state fits in ws.
    // Dataflow skew bound is <=2, so even D=4 is safe.
    int D = 32;
    while (D > 4 &&
           OFF_AB1 + (size_t)D * ((size_t)S1e + 2 * (size_t)S2e) > ws_size)
        D >>= 1;
    fp8* ab1 = (fp8*)(ws + OFF_AB1);
    fp8* ab2 = ab1 + (size_t)D * S1e;
    fp8* ab3 = ab2 + (size_t)D * S2e;

    (void)n_in;  // total need @D=32 ~= 59 MB, @D=16 ~= 45 MB

    hipLaunchKernelGGL(k_pack_w1, dim3(1024), dim3(256), 0, stream, Wih1, Whh1, pW1);
    hipLaunchKernelGGL(k_pack_w1g, dim3(4096), dim3(256), 0, stream,
                       Wih1, Whh1, Wd, pW1G);
    hipLaunchKernelGGL(k_pack_w23, dim3(1024), dim3(256), 0, stream, Wih2, Whh2, pW2);
    hipLaunchKernelGGL(k_pack_w23, dim3(1024), dim3(256), 0, stream, Wih3, Whh3, pW3);
    hipLaunchKernelGGL(k_pack_wd, dim3(704), dim3(256), 0, stream, Wd, pWD);
    hipLaunchKernelGGL(k_pack_bias, dim3(49), dim3(256), 0, stream,
                       bih1, bhh1, bih2, bhh2, bih3, bhh3, bd, pB1, pB2, pB3, pBD);
    hipLaunchKernelGGL(k_pack_b1g, dim3(16), dim3(256), 0, stream,
                       bih1, bhh1, Wih1, bd, pB1G);
    hipLaunchKernelGGL(k_init, dim3(2048), dim3(256), 0, stream,
                       ab1, ab2, ab3, cbp, bar, D);
    hipLaunchKernelGGL(k_stage0, dim3(22), dim3(256), 0, stream, xseq, ab1, T0);
    hipLaunchKernelGGL(k_lstm, dim3(NBLK), dim3(512), 0, stream,
                       xseq, out, pW1, pW1G, pW2, pW3, pWD,
                       pB1, pB1G, pB2, pB3, pBD,
                       ab1, ab2, ab3, cbp, bar, T0, T, D - 1);
    hipLaunchKernelGGL(k_copy_orig, dim3(1069), dim3(256), 0, stream, xseq, out, T, T0);
}

// Round 10
// 4788.860 us; speedup vs baseline: 1.1514x; 1.1514x over previous
//
#include <hip/hip_runtime.h>
#include <hip/hip_bf16.h>
#include <hip/hip_fp8.h>

// Problem constants (fixed by the bench: B=32, T0=50, F=171, H=1024, G=300)
#define Bn   32
#define Fdim 171
#define XPAD 256             // x-region padded to 16 tiles of 16 (conditioned phase)
#define Hdim 1024
#define NG   4096            // 4*H gate rows
#define K1p  1280            // layer1 conditioned K = XPAD+H (80 tiles)
#define K1g  2048            // layer1 generative K = H(h2 via Wcomb) + H(h0)
#define K2c  2048            // layer2/3 K = 2H (128 tiles)
#define KDd  1024            // decoder K = H
#define WDR  176             // decoder rows padded 171 -> 176
#define NBLK 192             // persistent grid: 3 layers x 64 unit-tiles
#define S1e  (80 * 512)      // ab1 slot BYTES (fp8, tiled [80][32][16])
#define S2e  (128 * 512)     // ab2/ab3 slot BYTES (tiled [128][32][16])

// fp8 scaling: weights *64, activations *16, both exact powers of 2.
#define SW    64.0f
#define SA    16.0f
#define INVS  (1.0f / (SW * SA))

typedef __attribute__((ext_vector_type(4))) float f32x4;
typedef unsigned char fp8;

// ---------------- static workspace layout (bytes); ab buffers are tail ----
#define ALIGN256(x) ((((size_t)(x)) + 255) & ~(size_t)255)
constexpr size_t OFF_W1  = 0;
constexpr size_t OFF_W1G = ALIGN256(OFF_W1 + (size_t)NG * K1p);
constexpr size_t OFF_W2  = ALIGN256(OFF_W1G + (size_t)NG * K1g);
constexpr size_t OFF_W3  = ALIGN256(OFF_W2 + (size_t)NG * K2c);
constexpr size_t OFF_WD  = ALIGN256(OFF_W3 + (size_t)NG * K2c);
constexpr size_t OFF_B1  = ALIGN256(OFF_WD + (size_t)WDR * KDd);
constexpr size_t OFF_B1G = ALIGN256(OFF_B1 + (size_t)NG * 4);
constexpr size_t OFF_B2  = ALIGN256(OFF_B1G + (size_t)NG * 4);
constexpr size_t OFF_B3  = ALIGN256(OFF_B2 + (size_t)NG * 4);
constexpr size_t OFF_BD  = ALIGN256(OFF_B3 + (size_t)NG * 4);
constexpr size_t OFF_CB  = ALIGN256(OFF_BD + (size_t)WDR * 4);
constexpr size_t OFF_BAR = ALIGN256(OFF_CB + (size_t)3 * Bn * Hdim * 4);
constexpr size_t OFF_AB1 = ALIGN256(OFF_BAR + 16384);   // bar region: 4096 u32
// ab1: D*S1e; ab2: D*S2e; ab3: D*S2e  (D chosen from ws_size; <=32)

// bar region word-offsets (all flags padded: one u32 per 64B line)
#define FLG(i)  ((i) * 16)          // arrival flags, 192 lines
#define RELW(m) (3072 + (m) * 16)   // 4 mirrored release words

// gate-interleaved packed row: pr = u*64 + q*16 + rr  <->  orig row = q*1024 + u*16 + rr
__device__ __forceinline__ int orig_row(int pr) {
    int u = pr >> 6, q = (pr >> 4) & 3, rr = pr & 15;
    return q * Hdim + u * 16 + rr;
}

__device__ __forceinline__ float sigm(float x) { return 1.f / (1.f + __expf(-x)); }
// overflow-safe fast tanh: e^{-2|x|} never overflows; large |c| -> +-1 exactly.
__device__ __forceinline__ float ftanh(float x) {
    float e = __expf(-2.f * fabsf(x));
    float t = (1.f - e) / (1.f + e);
    return x >= 0.f ? t : -t;
}

__device__ __forceinline__ unsigned char f2fp8(float x) {  // OCP e4m3, RNE+sat
    __hip_fp8_e4m3 q(x);
    return (unsigned char)q.__x;
}

__device__ __forceinline__ long ld8b(const fp8* p) {   // plain cached 8B load
    return *reinterpret_cast<const long*>(p);
}
// Coherent write-through stores (agent scope, relaxed): reach the coherence
// point, no cache-wide maintenance; readers use plain cached loads + rotation.
__device__ __forceinline__ void st1c(fp8* p, unsigned char v) {
    __hip_atomic_store((unsigned char*)p, v, __ATOMIC_RELAXED, __HIP_MEMORY_SCOPE_AGENT);
}
__device__ __forceinline__ void stu64(unsigned long long* p, unsigned long long v) {
    __hip_atomic_store(p, v, __ATOMIC_RELAXED, __HIP_MEMORY_SCOPE_AGENT);
}
__device__ __forceinline__ unsigned ldflag(const unsigned* p) {
    return __hip_atomic_load(p, __ATOMIC_RELAXED, __HIP_MEMORY_SCOPE_AGENT);
}
__device__ __forceinline__ void stflag(unsigned* p, unsigned v) {
    __hip_atomic_store(p, v, __ATOMIC_RELAXED, __HIP_MEMORY_SCOPE_AGENT);
}
__device__ __forceinline__ f32x4 mfma8(long a, long b, f32x4 c) {
    return __builtin_amdgcn_mfma_f32_16x16x32_fp8_fp8(a, b, c, 0, 0, 0);
}

// A-fragment loads from tiled [k/16][b][16] fp8 state
template <int NF>
__device__ __forceinline__ void aload(const fp8* __restrict__ As, int k0,
                                      int col, int kb8, long (&a0)[NF], long (&a1)[NF]) {
#pragma unroll
    for (int i = 0; i < NF; ++i) {
        int k = k0 + i * 32 + kb8;
        const fp8* ap = As + (size_t)(k >> 4) * 512 + (k & 15);
        a0[i] = ld8b(ap + col * 16);
        a1[i] = ld8b(ap + (col + 16) * 16);
    }
}
// weight stream + MFMA accumulate (weights row-linear [gate_row][K])
template <int K, int NF>
__device__ __forceinline__ void wstream(const fp8* __restrict__ Wrow, int k0,
                                        int col, int kb8,
                                        const long (&a0)[NF], const long (&a1)[NF],
                                        f32x4 (&acc)[2][4]) {
#pragma unroll
    for (int i = 0; i < NF; ++i) {
        const fp8* wp = Wrow + (size_t)col * K + k0 + i * 32 + kb8;
#pragma unroll
        for (int q = 0; q < 4; ++q) {
            long bq = ld8b(wp + (size_t)q * 16 * K);
            acc[0][q] = mfma8(a0[i], bq, acc[0][q]);
            acc[1][q] = mfma8(a1[i], bq, acc[1][q]);
        }
    }
}

// ---------------- prep kernels ----------------
__global__ void k_pack_w1(const float* Wih, const float* Whh, fp8* dst) {
    const size_t n = (size_t)NG * K1p;
    for (size_t i = (size_t)blockIdx.x * blockDim.x + threadIdx.x; i < n;
         i += (size_t)gridDim.x * blockDim.x) {
        int pr = (int)(i / K1p), k = (int)(i % K1p);
        int ro = orig_row(pr);
        float v = 0.f;
        if (k < Fdim)       v = Wih[(size_t)ro * Fdim + k];
        else if (k >= XPAD) v = Whh[(size_t)ro * Hdim + (k - XPAD)];
        dst[i] = f2fp8(v * SW);
    }
}

__global__ void k_pack_w23(const float* Wih, const float* Whh, fp8* dst) {
    const size_t n = (size_t)NG * K2c;
    for (size_t i = (size_t)blockIdx.x * blockDim.x + threadIdx.x; i < n;
         i += (size_t)gridDim.x * blockDim.x) {
        int pr = (int)(i / K2c), k = (int)(i % K2c);
        int ro = orig_row(pr);
        float v = (k < Hdim) ? Wih[(size_t)ro * Hdim + k]
                             : Whh[(size_t)ro * Hdim + (k - Hdim)];
        dst[i] = f2fp8(v * SW);
    }
}

// generative layer-1 weights: cols 0..1023 = Wcomb = W1x @ Wd  (decoder folded
// into the recurrence), cols 1024..2047 = Whh1.
__global__ void k_pack_w1g(const float* Wih, const float* Whh, const float* Wd,
                           fp8* dst) {
    const size_t n = (size_t)NG * K1g;
    for (size_t i = (size_t)blockIdx.x * blockDim.x + threadIdx.x; i < n;
         i += (size_t)gridDim.x * blockDim.x) {
        int pr = (int)(i >> 11), k = (int)(i & 2047);
        int ro = orig_row(pr);
        float v;
        if (k < 1024) {
            float acc = 0.f;
            for (int f = 0; f < Fdim; ++f)
                acc += Wih[(size_t)ro * Fdim + f] * Wd[(size_t)f * KDd + k];
            v = acc;
        } else {
            v = Whh[(size_t)ro * Hdim + (k - 1024)];
        }
        dst[i] = f2fp8(v * SW);
    }
}

__global__ void k_pack_wd(const float* Wd, fp8* dst) {
    const size_t n = (size_t)WDR * KDd;
    for (size_t i = (size_t)blockIdx.x * blockDim.x + threadIdx.x; i < n;
         i += (size_t)gridDim.x * blockDim.x) {
        int r = (int)(i / KDd), k = (int)(i % KDd);
        float v = (r < Fdim) ? Wd[(size_t)r * KDd + k] : 0.f;
        dst[i] = f2fp8(v * SW);
    }
}

__global__ void k_pack_bias(const float* bi1, const float* bh1,
                            const float* bi2, const float* bh2,
                            const float* bi3, const float* bh3,
                            const float* bd,
                            float* B1, float* B2, float* B3, float* BD) {
    const int n = 3 * NG + WDR;
    for (int i = blockIdx.x * blockDim.x + threadIdx.x; i < n;
         i += gridDim.x * blockDim.x) {
        if (i < NG)            { int ro = orig_row(i);        B1[i]        = bi1[ro] + bh1[ro]; }
        else if (i < 2 * NG)   { int ro = orig_row(i - NG);   B2[i - NG]   = bi2[ro] + bh2[ro]; }
        else if (i < 3 * NG)   { int ro = orig_row(i - 2*NG); B3[i - 2*NG] = bi3[ro] + bh3[ro]; }
        else { int r = i - 3 * NG; BD[r] = (r < Fdim) ? bd[r] : 0.f; }
    }
}

// b1g = b1 + W1x @ bd  (exact f32)
__global__ void k_pack_b1g(const float* bi1, const float* bh1,
                           const float* Wih, const float* bd, float* B1G) {
    for (int pr = blockIdx.x * blockDim.x + threadIdx.x; pr < NG;
         pr += gridDim.x * blockDim.x) {
        int ro = orig_row(pr);
        float acc = bi1[ro] + bh1[ro];
        for (int f = 0; f < Fdim; ++f)
            acc += Wih[(size_t)ro * Fdim + f] * bd[f];
        B1G[pr] = acc;
    }
}

// zero all rotating state slots with coherent stores (no cached copies anywhere)
__global__ void k_init(fp8* ab1, fp8* ab2, fp8* ab3, float* cb, unsigned* bar, int D) {
    const size_t n1 = (size_t)D * (S1e / 8);   // u64 count
    const size_t n2 = (size_t)D * (S2e / 8);
    const size_t nc = 3 * Bn * Hdim;
    const size_t tot = n1 + 2 * n2 + nc + 4096;
    for (size_t i = (size_t)blockIdx.x * blockDim.x + threadIdx.x; i < tot;
         i += (size_t)gridDim.x * blockDim.x) {
        if (i < n1)             stu64((unsigned long long*)ab1 + i, 0ull);
        else if (i < n1 + n2)   stu64((unsigned long long*)ab2 + (i - n1), 0ull);
        else if (i < n1 + 2*n2) stu64((unsigned long long*)ab3 + (i - n1 - n2), 0ull);
        else if (i < n1 + 2*n2 + nc) cb[i - n1 - 2*n2] = 0.f;
        else bar[i - n1 - 2*n2 - nc] = 0u;
    }
}

// stage x(0) into slot 0 (tiled layout), coherent, scaled by SA
__global__ void k_stage0(const float* xseq, fp8* ab1, int T0) {
    for (int idx = blockIdx.x * blockDim.x + threadIdx.x; idx < Bn * 11 * 16;
         idx += gridDim.x * blockDim.x) {
        int fu = idx >> 9, rem = idx & 511, b = rem >> 4, jj = rem & 15;
        int f = fu * 16 + jj;
        if (f < Fdim)
            st1c(&ab1[idx], f2fp8(xseq[(size_t)b * T0 * Fdim + f] * SA));
    }
}

__global__ void k_copy_orig(const float* xseq, float* out, int T, int T0) {
    const int n = Bn * T0 * Fdim;
    const size_t base = (size_t)Bn * T * Fdim;
    for (int i = blockIdx.x * blockDim.x + threadIdx.x; i < n;
         i += gridDim.x * blockDim.x) {
        out[base + i] = xseq[i];
    }
}

// ---------------- fence-free central-poller barrier ----------------
// Arrival: one relaxed store per block to its OWN 64B line. Block 0's wave-0
// scans all 192 lines, publishes 4 mirrored release words; other blocks poll
// ONE mirror with ONE lane (<=48 pollers/line).
__device__ __forceinline__ void gbar_all(unsigned* bar, unsigned target) {
    __syncthreads();   // per-wave vmcnt drain: all publish stores acked
    const int tid = threadIdx.x;
    const int bid = blockIdx.x;
    if (tid == 0)
        stflag(&bar[FLG(bid)], target);
    if (bid == 0) {
        if (tid < 64) {
            for (;;) {
                unsigned v0 = ldflag(&bar[FLG(tid)]);
                unsigned v1 = ldflag(&bar[FLG(tid + 64)]);
                unsigned v2 = ldflag(&bar[FLG(tid + 128)]);
                if (__all(v0 >= target && v1 >= target && v2 >= target)) break;
                __builtin_amdgcn_s_sleep(1);
            }
            if (tid < 4)
                stflag(&bar[RELW(tid)], target);
        }
    } else if (tid == 0) {
        unsigned* rp = &bar[RELW(bid & 3)];
        unsigned v;
        do {
            __builtin_amdgcn_s_sleep(2);
            v = ldflag(rp);
        } while (v < target);
    }
    asm volatile("" ::: "memory");
    __syncthreads();
}

// ---------------- persistent LSTM kernel ----------------
// grid = 192 x 512 threads (8 waves). block -> (layer = bid/64, ut = bid%64).
// ONE grid barrier per step; decoder folded (W1G/B1G) so no feedback chain.
// h publish: LDS-staged, then 64 x 8B agent-scope stores per destination
// (wave 0 -> dest0, wave 1 -> dest1) instead of 512 byte-stores x2 — cuts
// coherence-point per-line merge traffic 8x and far-store count 16x.
__global__ __launch_bounds__(512, 1) void k_lstm(
    const float* __restrict__ xseq, float* __restrict__ out,
    const fp8* __restrict__ W1, const fp8* __restrict__ W1G,
    const fp8* __restrict__ W2, const fp8* __restrict__ W3,
    const fp8* __restrict__ WD,
    const float* __restrict__ b1, const float* __restrict__ b1g,
    const float* __restrict__ b2, const float* __restrict__ b3,
    const float* __restrict__ bdp,
    fp8* ab1, fp8* ab2, fp8* ab3, float* cb,
    unsigned* bar, int T0, int T, int dm) {
    __shared__ float red[8][32][66];
    __shared__ fp8 hstage[512];
    __shared__ fp8 xstage[5632];

    const int tid = threadIdx.x;
    const int w = tid >> 6;
    const int lane = tid & 63;
    const int col = lane & 15;
    const int kb8 = (lane >> 4) << 3;
    const int bid = blockIdx.x;
    const int layer = bid >> 6;
    const int ut = bid & 63;
    const bool isdec = (bid >= 64 && bid < 75);  // decoder n-tile owners
    const int dnt = bid - 64;

    const float* bl0 = (layer == 0) ? b1 : (layer == 1) ? b2 : b3;
    fp8* abIn = (layer == 0) ? ab1 : (layer == 1) ? ab2 : ab3;
    const fp8* Wl = (layer == 1) ? W2 : W3;
    const size_t Sl = (layer == 0) ? (size_t)S1e : (size_t)S2e;

    // elementwise mapping: eb = w + 8*(lane>>4) makes BOTH the acc dump and
    // the 8-way reduce read conflict-free (2 lanes/bank).
    const int eb = w + 8 * (lane >> 4);
    const int ejj = lane & 15;
    const int off = eb * 16 + ejj;

    // publish destinations (block-constant)
    fp8* dst0s = (layer == 0) ? ab1 : (layer == 1) ? ab2 : ab3;
    const size_t d0off = (layer == 0) ? (size_t)(16 + ut) * 512
                                      : (size_t)(64 + ut) * 512;
    const size_t d0slot = (layer == 0) ? (size_t)S1e : (size_t)S2e;
    fp8* dst1s = (layer == 0) ? ab2 : (layer == 1) ? ab3 : nullptr;
    const size_t d1off = (size_t)ut * 512;

    // software-pipelined A fragments (K=2048 paths), loaded after each barrier
    long a0p[8], a1p[8];
    if (layer != 0) aload<8>(abIn, w * 256, col, kb8, a0p, a1p);  // slot 0, t=0

    for (int t = 0; t < T; ++t) {
        const int st = t & dm;
        const int ns = (t + 1) & dm;

        // ---------- phase A: gate GEMM ----------
        f32x4 acc[2][4] = {};
        if (layer == 0) {
            if (t < T0) {   // conditioned: x staged from xseq, K=1280
                const fp8* As = ab1 + (size_t)st * S1e;
                const fp8* Wrow = W1 + (size_t)(ut * 64) * K1p;
                long h0v[4], h1v[4];
                aload<4>(As, XPAD + w * 128, col, kb8, h0v, h1v);
                wstream<K1p, 4>(Wrow, XPAD + w * 128, col, kb8, h0v, h1v, acc);
                long x0[1], x1[1];
                aload<1>(As, w * 32, col, kb8, x0, x1);
                wstream<K1p, 1>(Wrow, w * 32, col, kb8, x0, x1, acc);
            } else {        // generative: Wcomb*h2 + Whh1*h0, K=2048 (prefetched)
                const fp8* Wrow = W1G + (size_t)(ut * 64) * K1g;
                wstream<K1g, 8>(Wrow, w * 256, col, kb8, a0p, a1p, acc);
            }
        } else {
            const fp8* Wrow = Wl + (size_t)(ut * 64) * K2c;
            wstream<K2c, 8>(Wrow, w * 256, col, kb8, a0p, a1p, acc);
        }

        __syncthreads();  // red[] free (previous readers done)
#pragma unroll
        for (int mt = 0; mt < 2; ++mt)
#pragma unroll
            for (int q = 0; q < 4; ++q)
#pragma unroll
                for (int r = 0; r < 4; ++r)
                    red[w][mt * 16 + (lane >> 4) * 4 + r][q * 16 + col] = acc[mt][q][r];
        __syncthreads();

        {   // gates + elementwise c/h update -> hstage (LDS)
            const float* bl = (layer == 0 && t >= T0) ? b1g : bl0;
            float s[4];
#pragma unroll
            for (int q = 0; q < 4; ++q) {
                float a = 0.f;
#pragma unroll
                for (int ww = 0; ww < 8; ++ww) a += red[ww][eb][q * 16 + ejj];
                s[q] = a * INVS + bl[ut * 64 + q * 16 + ejj];
            }
            size_t cidx = ((size_t)layer * Bn + eb) * Hdim + ut * 16 + ejj;
            float cold = cb[cidx];
            float cn = sigm(s[1]) * cold + sigm(s[0]) * ftanh(s[2]);
            float hn = sigm(s[3]) * ftanh(cn);
            cb[cidx] = cn;
            hstage[off] = f2fp8(hn * SA);
        }

        // conditioned x(t+1): compute into xstage (LDS), publish wide below
        if (bid == 11 && t + 1 < T0) {
            for (int idx = tid; idx < Bn * 11 * 16; idx += 512) {
                int fu = idx >> 9, rem = idx & 511, b = rem >> 4, jj = rem & 15;
                int f = fu * 16 + jj;
                xstage[idx] = (f < Fdim)
                    ? f2fp8(xseq[((size_t)b * T0 + t + 1) * Fdim + f] * SA)
                    : (fp8)0;
            }
        }

        __syncthreads();  // hstage/xstage complete

        // ---------- wide coherent publish (8B stores) ----------
        if (tid < 64) {
            unsigned long long v =
                *reinterpret_cast<unsigned long long*>(&hstage[tid * 8]);
            stu64((unsigned long long*)(dst0s + (size_t)ns * d0slot + d0off + tid * 8), v);
        } else if (tid < 128 && dst1s != nullptr) {
            unsigned long long v =
                *reinterpret_cast<unsigned long long*>(&hstage[(tid - 64) * 8]);
            stu64((unsigned long long*)(dst1s + (size_t)ns * S2e + d1off + (tid - 64) * 8), v);
        }
        if (bid == 11 && t + 1 < T0 && tid < 128) {
            fp8* dst = ab1 + (size_t)ns * S1e;
            for (int i8 = tid; i8 < 704; i8 += 128) {
                unsigned long long v =
                    *reinterpret_cast<unsigned long long*>(&xstage[i8 * 8]);
                stu64((unsigned long long*)(dst + i8 * 8), v);
            }
        }

        gbar_all(bar, (unsigned)(t + 1));

        // prefetch next-step A fragments (producers done at barrier)
        if (layer != 0) {
            aload<8>(abIn + (size_t)ns * Sl, w * 256, col, kb8, a0p, a1p);
        } else if (t + 1 >= T0) {
            const fp8* Ab = (w < 4) ? ab3 + (size_t)ns * S2e + 64 * 512
                                    : ab1 + (size_t)ns * S1e + 16 * 512;
            aload<8>(Ab, (w & 3) * 256, col, kb8, a0p, a1p);
        }

        // ---------- decoder: out(t) = h2(t) @ Wd^T + bd (off critical path) ----------
        if (isdec) {
            const fp8* Ad = ab3 + (size_t)ns * S2e + 64 * 512;  // h2 tiles
            const fp8* Wrowd = WD + (size_t)(dnt * 16) * KDd;
            long d0[4], d1[4];
            aload<4>(Ad, w * 128, col, kb8, d0, d1);
            f32x4 dacc[2] = {};
#pragma unroll
            for (int i = 0; i < 4; ++i) {
                long bq = ld8b(Wrowd + (size_t)col * KDd + w * 128 + i * 32 + kb8);
                dacc[0] = mfma8(d0[i], bq, dacc[0]);
                dacc[1] = mfma8(d1[i], bq, dacc[1]);
            }
            __syncthreads();
#pragma unroll
            for (int mt = 0; mt < 2; ++mt)
#pragma unroll
                for (int r = 0; r < 4; ++r)
                    red[w][mt * 16 + (lane >> 4) * 4 + r][col] = dacc[mt][r];
            __syncthreads();
            {
                int f = dnt * 16 + ejj;
                float v = 0.f;
#pragma unroll
                for (int ww = 0; ww < 8; ++ww) v += red[ww][eb][ejj];
                v = v * INVS + bdp[f];
                if (f < Fdim)
                    out[(size_t)eb * ((size_t)T * Fdim) + (size_t)t * Fdim + f] = v;
            }
        }
    }
}

// ---------------- host launch ----------------
extern "C" void kernel_launch(void* const* d_in, const int* in_sizes, int n_in,
                              void* d_out, int out_size, void* d_ws, size_t ws_size,
                              hipStream_t stream) {
    const float* xseq = (const float*)d_in[0];
    const float* Wih1 = (const float*)d_in[2];
    const float* Whh1 = (const float*)d_in[3];
    const float* bih1 = (const float*)d_in[4];
    const float* bhh1 = (const float*)d_in[5];
    const float* Wih2 = (const float*)d_in[6];
    const float* Whh2 = (const float*)d_in[7];
    const float* bih2 = (const float*)d_in[8];
    const float* bhh2 = (const float*)d_in[9];
    const float* Wih3 = (const float*)d_in[10];
    const float* Whh3 = (const float*)d_in[11];
    const float* bih3 = (const float*)d_in[12];
    const float* bhh3 = (const float*)d_in[13];
    const float* Wd   = (const float*)d_in[14];
    const float* bd   = (const float*)d_in[15];

    const int T0 = in_sizes[0] / (Bn * Fdim);                 // 50
    const int T  = out_size / (Bn * Fdim) - T0;               // 350

    char* ws = (char*)d_ws;
    fp8*   pW1  = (fp8*)(ws + OFF_W1);
    fp8*   pW1G = (fp8*)(ws + OFF_W1G);
    fp8*   pW2  = (fp8*)(ws + OFF_W2);
    fp8*   pW3  = (fp8*)(ws + OFF_W3);
    fp8*   pWD  = (fp8*)(ws + OFF_WD);
    float* pB1  = (float*)(ws + OFF_B1);
    float* pB1G = (float*)(ws + OFF_B1G);
    float* pB2  = (float*)(ws + OFF_B2);
    float* pB3  = (float*)(ws + OFF_B3);
    float* pBD  = (float*)(ws + OFF_BD);
    float* cbp  = (float*)(ws + OFF_CB);
    unsigned* bar = (unsigned*)(ws + OFF_BAR);
    float* out = (float*)d_out;

    // rotation depth: largest power-of-2 D (<=32) whose state fits in ws
    int D = 32;
    while (D > 4 &&
           OFF_AB1 + (size_t)D * ((size_t)S1e + 2 * (size_t)S2e) > ws_size)
        D >>= 1;
    fp8* ab1 = (fp8*)(ws + OFF_AB1);
    fp8* ab2 = ab1 + (size_t)D * S1e;
    fp8* ab3 = ab2 + (size_t)D * S2e;

    (void)n_in;  // total need @D=32 ~= 59 MB, @D=16 ~= 45 MB

    hipLaunchKernelGGL(k_pack_w1, dim3(1024), dim3(256), 0, stream, Wih1, Whh1, pW1);
    hipLaunchKernelGGL(k_pack_w1g, dim3(4096), dim3(256), 0, stream,
                       Wih1, Whh1, Wd, pW1G);
    hipLaunchKernelGGL(k_pack_w23, dim3(1024), dim3(256), 0, stream, Wih2, Whh2, pW2);
    hipLaunchKernelGGL(k_pack_w23, dim3(1024), dim3(256), 0, stream, Wih3, Whh3, pW3);
    hipLaunchKernelGGL(k_pack_wd, dim3(704), dim3(256), 0, stream, Wd, pWD);
    hipLaunchKernelGGL(k_pack_bias, dim3(49), dim3(256), 0, stream,
                       bih1, bhh1, bih2, bhh2, bih3, bhh3, bd, pB1, pB2, pB3, pBD);
    hipLaunchKernelGGL(k_pack_b1g, dim3(16), dim3(256), 0, stream,
                       bih1, bhh1, Wih1, bd, pB1G);
    hipLaunchKernelGGL(k_init, dim3(2048), dim3(256), 0, stream,
                       ab1, ab2, ab3, cbp, bar, D);
    hipLaunchKernelGGL(k_stage0, dim3(22), dim3(256), 0, stream, xseq, ab1, T0);
    hipLaunchKernelGGL(k_lstm, dim3(NBLK), dim3(512), 0, stream,
                       xseq, out, pW1, pW1G, pW2, pW3, pWD,
                       pB1, pB1G, pB2, pB3, pBD,
                       ab1, ab2, ab3, cbp, bar, T0, T, D - 1);
    hipLaunchKernelGGL(k_copy_orig, dim3(1069), dim3(256), 0, stream, xseq, out, T, T0);
}

// Round 11
// 2570.390 us; speedup vs baseline: 2.1452x; 1.8631x over previous
//
#include <hip/hip_runtime.h>
#include <hip/hip_bf16.h>
#include <hip/hip_fp8.h>

// Problem constants (fixed by the bench: B=32, T0=50, F=171, H=1024, G=300)
#define Bn   32
#define Fdim 171
#define XPAD 256             // x-region padded to 16 tiles of 16 (conditioned phase)
#define Hdim 1024
#define NG   4096            // 4*H gate rows
#define K1K  1536            // layer1 conditioned K padded (x|pad|h|pad), 6 chunks/wave
#define K1g  2048            // layer1 generative K = H(h2 via Wcomb) + H(h0)
#define K2c  2048            // layer2/3 K = 2H
#define KDd  1024            // decoder K = H
#define WDR  176             // decoder rows padded 171 -> 176
#define NBLK 192             // worker blocks: 3 layers x 64 unit-tiles (+1 aggregator)
#define S1e  (80 * 512)      // ab1 slot BYTES (fp8, tiled [80][32][16], k<1280)
#define S2e  (128 * 512)     // ab2/ab3 slot BYTES (tiled [128][32][16])

// fp8 scaling: weights *64, activations *16, both exact powers of 2.
#define SW    64.0f
#define SA    16.0f
#define INVS  (1.0f / (SW * SA))

typedef __attribute__((ext_vector_type(4))) float f32x4;
typedef __attribute__((ext_vector_type(2))) long lx2;
typedef unsigned char fp8;

// ---------------- static workspace layout (bytes); ab buffers are tail ----
#define ALIGN256(x) ((((size_t)(x)) + 255) & ~(size_t)255)
constexpr size_t OFF_W1  = 0;                                       // packed, 4096*1536
constexpr size_t OFF_W1G = ALIGN256(OFF_W1 + (size_t)NG * K1K);     // packed, 4096*2048
constexpr size_t OFF_W2  = ALIGN256(OFF_W1G + (size_t)NG * K1g);
constexpr size_t OFF_W3  = ALIGN256(OFF_W2 + (size_t)NG * K2c);
constexpr size_t OFF_WD  = ALIGN256(OFF_W3 + (size_t)NG * K2c);     // old row-linear
constexpr size_t OFF_B1  = ALIGN256(OFF_WD + (size_t)WDR * KDd);
constexpr size_t OFF_B1G = ALIGN256(OFF_B1 + (size_t)NG * 4);
constexpr size_t OFF_B2  = ALIGN256(OFF_B1G + (size_t)NG * 4);
constexpr size_t OFF_B3  = ALIGN256(OFF_B2 + (size_t)NG * 4);
constexpr size_t OFF_BD  = ALIGN256(OFF_B3 + (size_t)NG * 4);
constexpr size_t OFF_CB  = ALIGN256(OFF_BD + (size_t)WDR * 4);
constexpr size_t OFF_BAR = ALIGN256(OFF_CB + (size_t)3 * Bn * Hdim * 4);
constexpr size_t OFF_AB1 = ALIGN256(OFF_BAR + 16384);   // bar region: 4096 u32

// flags: one u32 per 64B line. flag[b]=t+1 <=> block b finished step t.
#define FLG(i)   ((i) * 16)                 // 192 arrival flags
#define LPW(l,m) (3072 + ((l) * 4 + (m)) * 16)   // per-layer progress, 4 mirrors

// gate-interleaved packed row: pr = u*64 + q*16 + rr  <->  orig row = q*1024 + u*16 + rr
__device__ __forceinline__ int orig_row(int pr) {
    int u = pr >> 6, q = (pr >> 4) & 3, rr = pr & 15;
    return q * Hdim + u * 16 + rr;
}

__device__ __forceinline__ float sigm(float x) { return 1.f / (1.f + __expf(-x)); }
__device__ __forceinline__ float ftanh(float x) {   // overflow-safe fast tanh
    float e = __expf(-2.f * fabsf(x));
    float t = (1.f - e) / (1.f + e);
    return x >= 0.f ? t : -t;
}

__device__ __forceinline__ unsigned char f2fp8(float x) {  // OCP e4m3, RNE+sat
    __hip_fp8_e4m3 q(x);
    return (unsigned char)q.__x;
}

__device__ __forceinline__ long ld8b(const fp8* p) {   // plain cached 8B load
    return *reinterpret_cast<const long*>(p);
}
// Coherent write-through ops (agent scope, relaxed): no cache-wide maintenance.
__device__ __forceinline__ void st1c(fp8* p, unsigned char v) {
    __hip_atomic_store((unsigned char*)p, v, __ATOMIC_RELAXED, __HIP_MEMORY_SCOPE_AGENT);
}
__device__ __forceinline__ void stu64(unsigned long long* p, unsigned long long v) {
    __hip_atomic_store(p, v, __ATOMIC_RELAXED, __HIP_MEMORY_SCOPE_AGENT);
}
__device__ __forceinline__ unsigned ldflag(const unsigned* p) {
    return __hip_atomic_load(p, __ATOMIC_RELAXED, __HIP_MEMORY_SCOPE_AGENT);
}
__device__ __forceinline__ void stflag(unsigned* p, unsigned v) {
    __hip_atomic_store(p, v, __ATOMIC_RELAXED, __HIP_MEMORY_SCOPE_AGENT);
}
__device__ __forceinline__ f32x4 mfma8(long a, long b, f32x4 c) {
    return __builtin_amdgcn_mfma_f32_16x16x32_fp8_fp8(a, b, c, 0, 0, 0);
}

// A-fragment loads from tiled [k/16][b][16] fp8 state
template <int NF>
__device__ __forceinline__ void aload(const fp8* __restrict__ As, int k0,
                                      int col, int kb8, long (&a0)[NF], long (&a1)[NF]) {
#pragma unroll
    for (int i = 0; i < NF; ++i) {
        int k = k0 + i * 32 + kb8;
        const fp8* ap = As + (size_t)(k >> 4) * 512 + (k & 15);
        a0[i] = ld8b(ap + col * 16);
        a1[i] = ld8b(ap + (col + 16) * 16);
    }
}

// packed weight stream: per (i2,q) ONE 16B/lane load = 1KB/wave fully-used
// (two K-chunks per instruction) -> half the L2 line-requests of the row-
// scattered 8B loads.
template <int NP>
__device__ __forceinline__ void wstream_pk(const fp8* __restrict__ wwave, int lane,
                                           const long (&a0)[2 * NP],
                                           const long (&a1)[2 * NP],
                                           f32x4 (&acc)[2][4]) {
#pragma unroll
    for (int i2 = 0; i2 < NP; ++i2) {
        const fp8* p = wwave + i2 * 4096 + lane * 16;
#pragma unroll
        for (int q = 0; q < 4; ++q) {
            lx2 wv = *reinterpret_cast<const lx2*>(p + q * 1024);
            acc[0][q] = mfma8(a0[2 * i2],     wv[0], acc[0][q]);
            acc[1][q] = mfma8(a1[2 * i2],     wv[0], acc[1][q]);
            acc[0][q] = mfma8(a0[2 * i2 + 1], wv[1], acc[0][q]);
            acc[1][q] = mfma8(a1[2 * i2 + 1], wv[1], acc[1][q]);
        }
    }
}

// ---------------- prep kernels ----------------
// fragment-order packer. dst[idx]: idx = ut*(64*Kpk) + w*(8*Kpk) + i2*4096
//   + q*1024 + lane*16 + b ; holds W[row=ut*64+q*16+(lane&15)]
//   [k = w*(Kpk/8) + (2*i2+(b>>3))*32 + (lane>>4)*8 + (b&7)]
// mode 0: W1 conditioned (x|pad|h|pad), 1: W1G (Wcomb|Whh1), 2: W2/W3 (Wih|Whh)
__global__ void k_pack_pk(int mode, const float* Wih, const float* Whh,
                          const float* Wd, fp8* dst, int Kpk) {
    const size_t n = (size_t)NG * Kpk;
    const int kq = Kpk >> 3;
    for (size_t idx = (size_t)blockIdx.x * blockDim.x + threadIdx.x; idx < n;
         idx += (size_t)gridDim.x * blockDim.x) {
        int ut = (int)(idx / ((size_t)64 * Kpk));
        int rem = (int)(idx % ((size_t)64 * Kpk));
        int w = rem / (8 * Kpk);
        int rem2 = rem % (8 * Kpk);
        int i2 = rem2 >> 12;
        int q = (rem2 >> 10) & 3;
        int lane = (rem2 >> 4) & 63;
        int b = rem2 & 15;
        int ro = orig_row(ut * 64 + q * 16 + (lane & 15));
        int k = w * kq + (2 * i2 + (b >> 3)) * 32 + ((lane >> 4) << 3) + (b & 7);
        float v = 0.f;
        if (mode == 0) {
            if (k < Fdim) v = Wih[(size_t)ro * Fdim + k];
            else if (k >= XPAD && k < XPAD + Hdim) v = Whh[(size_t)ro * Hdim + (k - XPAD)];
        } else if (mode == 1) {
            if (k < Hdim) {
                float a = 0.f;
                for (int f = 0; f < Fdim; ++f)
                    a += Wih[(size_t)ro * Fdim + f] * Wd[(size_t)f * KDd + k];
                v = a;
            } else {
                v = Whh[(size_t)ro * Hdim + (k - Hdim)];
            }
        } else {
            v = (k < Hdim) ? Wih[(size_t)ro * Hdim + k]
                           : Whh[(size_t)ro * Hdim + (k - Hdim)];
        }
        dst[idx] = f2fp8(v * SW);
    }
}

__global__ void k_pack_wd(const float* Wd, fp8* dst) {
    const size_t n = (size_t)WDR * KDd;
    for (size_t i = (size_t)blockIdx.x * blockDim.x + threadIdx.x; i < n;
         i += (size_t)gridDim.x * blockDim.x) {
        int r = (int)(i / KDd), k = (int)(i % KDd);
        float v = (r < Fdim) ? Wd[(size_t)r * KDd + k] : 0.f;
        dst[i] = f2fp8(v * SW);
    }
}

__global__ void k_pack_bias(const float* bi1, const float* bh1,
                            const float* bi2, const float* bh2,
                            const float* bi3, const float* bh3,
                            const float* bd,
                            float* B1, float* B2, float* B3, float* BD) {
    const int n = 3 * NG + WDR;
    for (int i = blockIdx.x * blockDim.x + threadIdx.x; i < n;
         i += gridDim.x * blockDim.x) {
        if (i < NG)            { int ro = orig_row(i);        B1[i]        = bi1[ro] + bh1[ro]; }
        else if (i < 2 * NG)   { int ro = orig_row(i - NG);   B2[i - NG]   = bi2[ro] + bh2[ro]; }
        else if (i < 3 * NG)   { int ro = orig_row(i - 2*NG); B3[i - 2*NG] = bi3[ro] + bh3[ro]; }
        else { int r = i - 3 * NG; BD[r] = (r < Fdim) ? bd[r] : 0.f; }
    }
}

// b1g = b1 + W1x @ bd  (exact f32)
__global__ void k_pack_b1g(const float* bi1, const float* bh1,
                           const float* Wih, const float* bd, float* B1G) {
    for (int pr = blockIdx.x * blockDim.x + threadIdx.x; pr < NG;
         pr += gridDim.x * blockDim.x) {
        int ro = orig_row(pr);
        float acc = bi1[ro] + bh1[ro];
        for (int f = 0; f < Fdim; ++f)
            acc += Wih[(size_t)ro * Fdim + f] * bd[f];
        B1G[pr] = acc;
    }
}

// zero all rotating state slots with coherent stores (no cached copies anywhere)
__global__ void k_init(fp8* ab1, fp8* ab2, fp8* ab3, float* cb, unsigned* bar, int D) {
    const size_t n1 = (size_t)D * (S1e / 8);   // u64 count
    const size_t n2 = (size_t)D * (S2e / 8);
    const size_t nc = 3 * Bn * Hdim;
    const size_t tot = n1 + 2 * n2 + nc + 4096;
    for (size_t i = (size_t)blockIdx.x * blockDim.x + threadIdx.x; i < tot;
         i += (size_t)gridDim.x * blockDim.x) {
        if (i < n1)             stu64((unsigned long long*)ab1 + i, 0ull);
        else if (i < n1 + n2)   stu64((unsigned long long*)ab2 + (i - n1), 0ull);
        else if (i < n1 + 2*n2) stu64((unsigned long long*)ab3 + (i - n1 - n2), 0ull);
        else if (i < n1 + 2*n2 + nc) cb[i - n1 - 2*n2] = 0.f;
        else bar[i - n1 - 2*n2 - nc] = 0u;
    }
}

// stage x(0) into slot 0 (tiled layout), coherent, scaled by SA
__global__ void k_stage0(const float* xseq, fp8* ab1, int T0) {
    for (int idx = blockIdx.x * blockDim.x + threadIdx.x; idx < Bn * 11 * 16;
         idx += gridDim.x * blockDim.x) {
        int fu = idx >> 9, rem = idx & 511, b = rem >> 4, jj = rem & 15;
        int f = fu * 16 + jj;
        if (f < Fdim)
            st1c(&ab1[idx], f2fp8(xseq[(size_t)b * T0 * Fdim + f] * SA));
    }
}

__global__ void k_copy_orig(const float* xseq, float* out, int T, int T0) {
    const int n = Bn * T0 * Fdim;
    const size_t base = (size_t)Bn * T * Fdim;
    for (int i = blockIdx.x * blockDim.x + threadIdx.x; i < n;
         i += gridDim.x * blockDim.x) {
        out[base + i] = xseq[i];
    }
}

// wave-0 poll: lane0 waits LP[la] >= tgt, lane1 waits LP[lb] >= tgt (mirror m)
__device__ __forceinline__ void pollLP(unsigned* bar, int la, int lb,
                                       unsigned tgt, int lane, int m) {
    for (;;) {
        bool ok = true;
        if (lane == 0) ok = (ldflag(&bar[LPW(la, m)]) >= tgt);
        else if (lane == 1 && lb >= 0) ok = (ldflag(&bar[LPW(lb, m)]) >= tgt);
        if (__all(ok)) break;
        __builtin_amdgcn_s_sleep(1);
    }
    asm volatile("" ::: "memory");
}

// ---------------- persistent LSTM kernel (aggregated dataflow sync) --------
// grid = NBLK+1 x 512. Workers: block -> (layer = bid/64, ut = bid%64).
// Block NBLK = aggregator: 3 waves continuously scan the 64 arrival flags of
// one layer each; when all >= tgt they publish LP[layer]=tgt to 4 mirrored
// lines and advance. Workers poll ONLY their 2 source-layer LP mirrors with
// 2 lanes (no global barrier; layers pipeline with skew <= 2; D=32 slots).
__global__ __launch_bounds__(512, 1) void k_lstm(
    const float* __restrict__ xseq, float* __restrict__ out,
    const fp8* __restrict__ W1, const fp8* __restrict__ W1G,
    const fp8* __restrict__ W2, const fp8* __restrict__ W3,
    const fp8* __restrict__ WD,
    const float* __restrict__ b1, const float* __restrict__ b1g,
    const float* __restrict__ b2, const float* __restrict__ b3,
    const float* __restrict__ bdp,
    fp8* ab1, fp8* ab2, fp8* ab3, float* cb,
    unsigned* bar, int T0, int T, int dm) {
    __shared__ float red[8][32][66];
    __shared__ fp8 hstage[512];
    __shared__ fp8 xstage[5632];

    const int tid = threadIdx.x;
    const int w = tid >> 6;
    const int lane = tid & 63;
    const int bid = blockIdx.x;

    // ---------------- aggregator block ----------------
    if (bid == NBLK) {
        if (w < 3) {
            unsigned tgt = 1;
            const unsigned* fp = &bar[FLG(64 * w + lane)];
            while (tgt <= (unsigned)T) {
                unsigned v = ldflag(fp);
                if (__all(v >= tgt)) {
                    if (lane < 4) stflag(&bar[LPW(w, lane)], tgt);
                    ++tgt;
                } else {
                    __builtin_amdgcn_s_sleep(1);
                }
            }
        }
        return;
    }

    const int col = lane & 15;
    const int kb8 = (lane >> 4) << 3;
    const int layer = bid >> 6;
    const int ut = bid & 63;
    const bool isdec = (bid >= 64 && bid < 75);
    const int dnt = bid - 64;

    // elementwise mapping (conflict-free dump + reduce)
    const int eb = w + 8 * (lane >> 4);
    const int ejj = lane & 15;
    const int off = eb * 16 + ejj;

    // publish destinations (block-constant)
    fp8* dst0s = (layer == 0) ? ab1 : (layer == 1) ? ab2 : ab3;
    const size_t d0off = (layer == 0) ? (size_t)(16 + ut) * 512
                                      : (size_t)(64 + ut) * 512;
    const size_t d0slot = (layer == 0) ? (size_t)S1e : (size_t)S2e;
    fp8* dst1s = (layer == 0) ? ab2 : (layer == 1) ? ab3 : nullptr;
    const size_t d1off = (size_t)ut * 512;

    for (int t = 0; t < T; ++t) {
        const int st = t & dm;
        const int ns = (t + 1) & dm;

        // ---------- wait for source layers (wave 0 only) ----------
        if (w == 0) {
            int la, lb = -1;
            if (layer == 0) { if (t < T0) { la = 0; } else { la = 2; lb = 0; } }
            else if (layer == 1) { la = 0; lb = 1; }
            else { la = 1; lb = 2; }
            pollLP(bar, la, lb, (unsigned)t, lane, bid & 3);
        }
        __syncthreads();

        // ---------- gate GEMM (packed weights) ----------
        f32x4 acc[2][4] = {};
        if (layer == 0) {
            if (t < T0) {
                const fp8* As = ab1 + (size_t)st * S1e;
                long a0[6], a1[6];
                aload<6>(As, w * (K1K / 8), col, kb8, a0, a1);
                wstream_pk<3>(W1 + (size_t)ut * 64 * K1K + (size_t)w * 8 * K1K,
                              lane, a0, a1, acc);
            } else {
                const fp8* Ah = (w < 4) ? ab3 + (size_t)st * S2e + 64 * 512
                                        : ab1 + (size_t)st * S1e + 16 * 512;
                long a0[8], a1[8];
                aload<8>(Ah, (w & 3) * 256, col, kb8, a0, a1);
                wstream_pk<4>(W1G + (size_t)ut * 64 * K1g + (size_t)w * 8 * K1g,
                              lane, a0, a1, acc);
            }
        } else if (layer == 1) {
            const fp8* As = ab2 + (size_t)st * S2e;
            long a0[8], a1[8];
            aload<8>(As, w * 256, col, kb8, a0, a1);
            wstream_pk<4>(W2 + (size_t)ut * 64 * K2c + (size_t)w * 8 * K2c,
                          lane, a0, a1, acc);
        } else {
            const fp8* As = ab3 + (size_t)st * S2e;
            long a0[8], a1[8];
            aload<8>(As, w * 256, col, kb8, a0, a1);
            wstream_pk<4>(W3 + (size_t)ut * 64 * K2c + (size_t)w * 8 * K2c,
                          lane, a0, a1, acc);
        }

        __syncthreads();
#pragma unroll
        for (int mt = 0; mt < 2; ++mt)
#pragma unroll
            for (int q = 0; q < 4; ++q)
#pragma unroll
                for (int r = 0; r < 4; ++r)
                    red[w][mt * 16 + (lane >> 4) * 4 + r][q * 16 + col] = acc[mt][q][r];
        __syncthreads();

        {   // gates + elementwise c/h update -> hstage (LDS)
            const float* bl = (layer == 0) ? ((t >= T0) ? b1g : b1)
                                           : (layer == 1) ? b2 : b3;
            float s[4];
#pragma unroll
            for (int q = 0; q < 4; ++q) {
                float a = 0.f;
#pragma unroll
                for (int ww = 0; ww < 8; ++ww) a += red[ww][eb][q * 16 + ejj];
                s[q] = a * INVS + bl[ut * 64 + q * 16 + ejj];
            }
            size_t cidx = ((size_t)layer * Bn + eb) * Hdim + ut * 16 + ejj;
            float cold = cb[cidx];
            float cn = sigm(s[1]) * cold + sigm(s[0]) * ftanh(s[2]);
            float hn = sigm(s[3]) * ftanh(cn);
            cb[cidx] = cn;
            hstage[off] = f2fp8(hn * SA);
        }

        if (bid == 11 && t + 1 < T0) {  // stage conditioned x(t+1) via LDS
            for (int idx = tid; idx < Bn * 11 * 16; idx += 512) {
                int fu = idx >> 9, rem = idx & 511, b = rem >> 4, jj = rem & 15;
                int f = fu * 16 + jj;
                xstage[idx] = (f < Fdim)
                    ? f2fp8(xseq[((size_t)b * T0 + t + 1) * Fdim + f] * SA)
                    : (fp8)0;
            }
        }

        __syncthreads();  // hstage/xstage complete

        // wide coherent publish (8B stores)
        if (tid < 64) {
            unsigned long long v =
                *reinterpret_cast<unsigned long long*>(&hstage[tid * 8]);
            stu64((unsigned long long*)(dst0s + (size_t)ns * d0slot + d0off + tid * 8), v);
        } else if (tid < 128 && dst1s != nullptr) {
            unsigned long long v =
                *reinterpret_cast<unsigned long long*>(&hstage[(tid - 64) * 8]);
            stu64((unsigned long long*)(dst1s + (size_t)ns * S2e + d1off + (tid - 64) * 8), v);
        }
        if (bid == 11 && t + 1 < T0 && tid < 128) {
            fp8* dst = ab1 + (size_t)ns * S1e;
            for (int i8 = tid; i8 < 704; i8 += 128) {
                unsigned long long v =
                    *reinterpret_cast<unsigned long long*>(&xstage[i8 * 8]);
                stu64((unsigned long long*)(dst + i8 * 8), v);
            }
        }

        __syncthreads();  // drain publish stores (vmcnt 0 at barrier)
        if (tid == 0) stflag(&bar[FLG(bid)], (unsigned)(t + 1));

        // ---------- decoder (blocks 64..74): out(t) = h2(t) @ Wd^T + bd ----------
        if (isdec) {
            if (w == 0) pollLP(bar, 2, -1, (unsigned)(t + 1), lane, bid & 3);
            __syncthreads();
            const fp8* Ad = ab3 + (size_t)ns * S2e + 64 * 512;
            const fp8* Wrowd = WD + (size_t)(dnt * 16) * KDd;
            long d0[4], d1[4];
            aload<4>(Ad, w * 128, col, kb8, d0, d1);
            f32x4 dacc[2] = {};
#pragma unroll
            for (int i = 0; i < 4; ++i) {
                long bq = ld8b(Wrowd + (size_t)col * KDd + w * 128 + i * 32 + kb8);
                dacc[0] = mfma8(d0[i], bq, dacc[0]);
                dacc[1] = mfma8(d1[i], bq, dacc[1]);
            }
            __syncthreads();
#pragma unroll
            for (int mt = 0; mt < 2; ++mt)
#pragma unroll
                for (int r = 0; r < 4; ++r)
                    red[w][mt * 16 + (lane >> 4) * 4 + r][col] = dacc[mt][r];
            __syncthreads();
            {
                int f = dnt * 16 + ejj;
                float v = 0.f;
#pragma unroll
                for (int ww = 0; ww < 8; ++ww) v += red[ww][eb][ejj];
                v = v * INVS + bdp[f];
                if (f < Fdim)
                    out[(size_t)eb * ((size_t)T * Fdim) + (size_t)t * Fdim + f] = v;
            }
        }
    }
}

// ---------------- host launch ----------------
extern "C" void kernel_launch(void* const* d_in, const int* in_sizes, int n_in,
                              void* d_out, int out_size, void* d_ws, size_t ws_size,
                              hipStream_t stream) {
    const float* xseq = (const float*)d_in[0];
    const float* Wih1 = (const float*)d_in[2];
    const float* Whh1 = (const float*)d_in[3];
    const float* bih1 = (const float*)d_in[4];
    const float* bhh1 = (const float*)d_in[5];
    const float* Wih2 = (const float*)d_in[6];
    const float* Whh2 = (const float*)d_in[7];
    const float* bih2 = (const float*)d_in[8];
    const float* bhh2 = (const float*)d_in[9];
    const float* Wih3 = (const float*)d_in[10];
    const float* Whh3 = (const float*)d_in[11];
    const float* bih3 = (const float*)d_in[12];
    const float* bhh3 = (const float*)d_in[13];
    const float* Wd   = (const float*)d_in[14];
    const float* bd   = (const float*)d_in[15];

    const int T0 = in_sizes[0] / (Bn * Fdim);                 // 50
    const int T  = out_size / (Bn * Fdim) - T0;               // 350

    char* ws = (char*)d_ws;
    fp8*   pW1  = (fp8*)(ws + OFF_W1);
    fp8*   pW1G = (fp8*)(ws + OFF_W1G);
    fp8*   pW2  = (fp8*)(ws + OFF_W2);
    fp8*   pW3  = (fp8*)(ws + OFF_W3);
    fp8*   pWD  = (fp8*)(ws + OFF_WD);
    float* pB1  = (float*)(ws + OFF_B1);
    float* pB1G = (float*)(ws + OFF_B1G);
    float* pB2  = (float*)(ws + OFF_B2);
    float* pB3  = (float*)(ws + OFF_B3);
    float* pBD  = (float*)(ws + OFF_BD);
    float* cbp  = (float*)(ws + OFF_CB);
    unsigned* bar = (unsigned*)(ws + OFF_BAR);
    float* out = (float*)d_out;

    // rotation depth: largest power-of-2 D (<=32) whose state fits in ws
    int D = 32;
    while (D > 4 &&
           OFF_AB1 + (size_t)D * ((size_t)S1e + 2 * (size_t)S2e) > ws_size)
        D >>= 1;
    fp8* ab1 = (fp8*)(ws + OFF_AB1);
    fp8* ab2 = ab1 + (size_t)D * S1e;
    fp8* ab3 = ab2 + (size_t)D * S2e;

    (void)n_in;  // total need @D=32 ~= 38 MB

    hipLaunchKernelGGL(k_pack_pk, dim3(1024), dim3(256), 0, stream,
                       0, Wih1, Whh1, Wd, pW1, K1K);
    hipLaunchKernelGGL(k_pack_pk, dim3(4096), dim3(256), 0, stream,
                       1, Wih1, Whh1, Wd, pW1G, K1g);
    hipLaunchKernelGGL(k_pack_pk, dim3(1024), dim3(256), 0, stream,
                       2, Wih2, Whh2, Wd, pW2, K2c);
    hipLaunchKernelGGL(k_pack_pk, dim3(1024), dim3(256), 0, stream,
                       2, Wih3, Whh3, Wd, pW3, K2c);
    hipLaunchKernelGGL(k_pack_wd, dim3(704), dim3(256), 0, stream, Wd, pWD);
    hipLaunchKernelGGL(k_pack_bias, dim3(49), dim3(256), 0, stream,
                       bih1, bhh1, bih2, bhh2, bih3, bhh3, bd, pB1, pB2, pB3, pBD);
    hipLaunchKernelGGL(k_pack_b1g, dim3(16), dim3(256), 0, stream,
                       bih1, bhh1, Wih1, bd, pB1G);
    hipLaunchKernelGGL(k_init, dim3(2048), dim3(256), 0, stream,
                       ab1, ab2, ab3, cbp, bar, D);
    hipLaunchKernelGGL(k_stage0, dim3(22), dim3(256), 0, stream, xseq, ab1, T0);
    hipLaunchKernelGGL(k_lstm, dim3(NBLK + 1), dim3(512), 0, stream,
                       xseq, out, pW1, pW1G, pW2, pW3, pWD,
                       pB1, pB1G, pB2, pB3, pBD,
                       ab1, ab2, ab3, cbp, bar, T0, T, D - 1);
    hipLaunchKernelGGL(k_copy_orig, dim3(1069), dim3(256), 0, stream, xseq, out, T, T0);
}